// Round 2
// baseline (16456.589 us; speedup 1.0000x reference)
//
#include <hip/hip_runtime.h>
#include <hip/hip_bf16.h>

// BiCLSTM: S=16,B=4,Cin=32,Co=32,H=W=128. fp32 in/out (per reference dtypes).
#define S_ 16
#define B_ 4
#define Cin_ 32
#define Co_ 32
#define H_ 128
#define W_ 128
#define HW_ (H_ * W_)

__device__ __forceinline__ float sigf(float x) { return 1.f / (1.f + __expf(-x)); }
__device__ __forceinline__ float tanhf_(float x) { return 2.f / (1.f + __expf(-2.f * x)) - 1.f; }

// Repack weights [co=128][ci=64][tap=9] f32 -> [ci=64][co=128][tap=9] f32
__global__ void prep_weights(const float* __restrict__ Wf,
                             const float* __restrict__ Wb,
                             float* __restrict__ wpf, float* __restrict__ wpb) {
    int i = blockIdx.x * 256 + threadIdx.x;
    if (i >= 128 * 64 * 9) return;
    int co = i / 576;
    int r = i - co * 576;
    int ci = r / 9;
    int tp = r - ci * 9;
    int d = (ci * 128 + co) * 9 + tp;
    wpf[d] = Wf[i];
    wpb[d] = Wb[i];
}

// One timestep, both directions. grid (8,8,8): x-tiles, y-tiles, z = dir*4 + b.
// h state lives in `out`: h(t-1) = out[t-1] slice (race-free: written by prev launch).
__global__ __launch_bounds__(256, 2)
void convlstm_step(const float* __restrict__ x,    // [S,B,32,H,W] f32
                   const float* __restrict__ wpf,  // [64][128][9] f32
                   const float* __restrict__ wpb,
                   const float* __restrict__ biasf,  // [128] f32
                   const float* __restrict__ biasb,
                   float* __restrict__ cst,   // [2][B][32][HW] f32
                   float* out,                // [S,B,64,H,W] f32 (h state + output)
                   int t) {
    const int zb = blockIdx.z;
    const int dir = zb >> 2;
    const int b = zb & 3;
    const int x0 = blockIdx.x * 16, y0 = blockIdx.y * 16;
    const int ts = dir ? (S_ - 1 - t) : t;

    const float* xt = x + (size_t)(ts * B_ + b) * Cin_ * HW_;
    const float* wp = dir ? wpb : wpf;
    const float* bias = dir ? biasb : biasf;
    float* c = cst + (size_t)(dir * B_ + b) * Co_ * HW_;
    float* outp = out + ((size_t)(t * B_ + b) * 64 + dir * 32) * HW_;
    const float* hprev = (t == 0) ? nullptr
                       : out + ((size_t)((t - 1) * B_ + b) * 64 + dir * 32) * HW_;

    __shared__ float sbuf[16 * 18 * 19];  // one 16-channel chunk, stride 19 (pad)

    const int tid = threadIdx.x;
    const int ty = tid >> 4, tx = tid & 15;

    float acc[128];
#pragma unroll
    for (int i = 0; i < 128; ++i) acc[i] = 0.f;

#pragma unroll 1
    for (int ck = 0; ck < 4; ++ck) {
        // chunk source: ck 0,1 -> x channels; ck 2,3 -> h(t-1) channels
        const float* src = (ck < 2) ? (xt + ck * 16 * HW_)
                                    : (hprev ? hprev + (ck - 2) * 16 * HW_ : nullptr);
        __syncthreads();
        for (int e = tid; e < 16 * 324; e += 256) {
            int ci = e / 324;
            int rem = e - ci * 324;
            int r = rem / 18, cc = rem - r * 18;
            int gy = y0 + r - 1, gx = x0 + cc - 1;
            float v = 0.f;
            if (src != nullptr && gy >= 0 && gy < H_ && gx >= 0 && gx < W_)
                v = src[ci * HW_ + gy * W_ + gx];
            sbuf[ci * 342 + r * 19 + cc] = v;
        }
        __syncthreads();

#pragma unroll 1
        for (int ci = 0; ci < 16; ++ci) {
            float vv[9];
            const float* base = sbuf + ci * 342 + ty * 19 + tx;
#pragma unroll
            for (int kh = 0; kh < 3; ++kh)
#pragma unroll
                for (int kw = 0; kw < 3; ++kw)
                    vv[kh * 3 + kw] = base[kh * 19 + kw];
            const float* w = wp + (ck * 16 + ci) * 1152;
#pragma unroll
            for (int co = 0; co < 128; ++co) {
#pragma unroll
                for (int tp = 0; tp < 9; ++tp)
                    acc[co] = fmaf(vv[tp], w[co * 9 + tp], acc[co]);
            }
        }
    }

    // LSTM epilogue: gates i,f,o,g = acc[q], acc[32+q], acc[64+q], acc[96+q]
    const int pix = (y0 + ty) * W_ + (x0 + tx);
#pragma unroll
    for (int q = 0; q < 32; ++q) {
        float zi = acc[q] + bias[q];
        float zf = acc[32 + q] + bias[32 + q];
        float zo = acc[64 + q] + bias[64 + q];
        float zg = acc[96 + q] + bias[96 + q];
        float cold = (t == 0) ? 0.f : c[q * HW_ + pix];
        float cn = sigf(zf) * cold + sigf(zi) * tanhf_(zg);
        float hn = sigf(zo) * tanhf_(cn);
        c[q * HW_ + pix] = cn;
        outp[q * HW_ + pix] = hn;
    }
}

extern "C" void kernel_launch(void* const* d_in, const int* in_sizes, int n_in,
                              void* d_out, int out_size, void* d_ws, size_t ws_size,
                              hipStream_t stream) {
    const float* x  = (const float*)d_in[0];
    const float* Wf = (const float*)d_in[1];
    const float* bf = (const float*)d_in[2];
    const float* Wb = (const float*)d_in[3];
    const float* bb = (const float*)d_in[4];
    float* out = (float*)d_out;
    char* ws = (char*)d_ws;

    float* wpf = (float*)(ws);                  // 294,912 B
    float* wpb = (float*)(ws + 294912);         // 294,912 B
    float* cst = (float*)(ws + 589824);         // 16,777,216 B

    prep_weights<<<dim3(288), dim3(256), 0, stream>>>(Wf, Wb, wpf, wpb);

    for (int t = 0; t < S_; ++t) {
        convlstm_step<<<dim3(8, 8, 8), dim3(256), 0, stream>>>(
            x, wpf, wpb, bf, bb, cst, out, t);
    }
}

// Round 3
// 2360.409 us; speedup vs baseline: 6.9719x; 6.9719x over previous
//
#include <hip/hip_runtime.h>

// BiCLSTM: S=16,B=4,Cin=32,Co=32,H=W=128. fp32 in/out.
// MFMA implicit-GEMM: M=pixels, N=128 gates, K=9 taps x 64 ci = 576.
// 3-pass bf16 hi/lo split for ~fp32 accuracy.
#define S_ 16
#define B_ 4
#define H_ 128
#define W_ 128
#define HW_ (H_ * W_)

typedef __attribute__((ext_vector_type(8))) short short8;
typedef __attribute__((ext_vector_type(4))) float f32x4;

__device__ __forceinline__ float bf2f(unsigned short u) {
    union { unsigned int i; float f; } v; v.i = ((unsigned int)u) << 16; return v.f;
}
__device__ __forceinline__ unsigned short f2bf(float f) {
    union { float f; unsigned int i; } v; v.f = f;
    unsigned int r = v.i + 0x7FFFu + ((v.i >> 16) & 1u);
    return (unsigned short)(r >> 16);
}
__device__ __forceinline__ float sigf(float x) { return 1.f / (1.f + __expf(-x)); }
__device__ __forceinline__ float tanhf_(float x) { return 2.f / (1.f + __expf(-2.f * x)) - 1.f; }

// Pack weights into MFMA B-fragment order, split hi/lo bf16.
// wpk: 4 streams [dir][s] each [ks=18][nf=8][lane=64][e=8] bf16 (147,456 B).
// K order: ks = tap*2 + half; k_local = (lane>>4)*8+e; ci = half*32 + k_local.
__global__ void prep_pack(const float* __restrict__ Wf, const float* __restrict__ Wb,
                          unsigned short* __restrict__ wpk) {
    int id = blockIdx.x * 256 + threadIdx.x;  // 2*18*8*64 = 18432
    if (id >= 18432) return;
    int l = id & 63;
    int nf = (id >> 6) & 7;
    int ks = (id >> 9) % 18;
    int d = id / 9216;
    const float* Wsrc = d ? Wb : Wf;
    int tap = ks >> 1, half = ks & 1;
    int dy = tap / 3, dx = tap - dy * 3;
    int co = nf * 16 + (l & 15);
    unsigned short hi8[8], lo8[8];
#pragma unroll
    for (int e = 0; e < 8; ++e) {
        int ci = half * 32 + (l >> 4) * 8 + e;
        float v = Wsrc[((co * 64 + ci) * 3 + dy) * 3 + dx];
        unsigned short h = f2bf(v);
        hi8[e] = h;
        lo8[e] = f2bf(v - bf2f(h));
    }
    size_t fo = ((size_t)(ks * 8 + nf) * 64 + l) * 8;
    unsigned short* dst_hi = wpk + (size_t)(d * 2 + 0) * 73728 + fo;
    unsigned short* dst_lo = wpk + (size_t)(d * 2 + 1) * 73728 + fo;
#pragma unroll
    for (int e = 0; e < 8; ++e) { dst_hi[e] = hi8[e]; dst_lo[e] = lo8[e]; }
}

// Stage 18x18 halo tile, 64 ci (0-31 = x, 32-63 = h(t-1)), as bf16 hi (p=0) or lo (p=1).
// LDS layout [row][col][ci padded to 72].
__device__ __forceinline__ void stage_tile(unsigned short* lds, const float* __restrict__ xt,
                                           const float* __restrict__ hprev,
                                           int x0, int y0, int tid, int p) {
    for (int idx = tid; idx < 324 * 64; idx += 256) {
        int ci = idx / 324;
        int rem = idx - ci * 324;
        int r = rem / 18;
        int cc = rem - r * 18;
        int gy = y0 + r - 1, gx = x0 + cc - 1;
        float v = 0.f;
        if ((unsigned)gy < 128u && (unsigned)gx < 128u) {
            if (ci < 32) v = xt[ci * HW_ + gy * W_ + gx];
            else if (hprev) v = hprev[(ci - 32) * HW_ + gy * W_ + gx];
        }
        unsigned short u = f2bf(v);
        if (p) u = f2bf(v - bf2f(u));
        lds[(r * 18 + cc) * 72 + ci] = u;
    }
}

template <int NB>
__device__ __forceinline__ void compute_pass(f32x4 (&acc)[4][8], const unsigned short* lds,
                                             const unsigned short* __restrict__ w0,
                                             const unsigned short* __restrict__ w1,
                                             int lane, int wq) {
    const int px = lane & 15, kg = lane >> 4;
#pragma unroll 1
    for (int ks = 0; ks < 18; ++ks) {
        int tap = ks >> 1, half = ks & 1;
        int dy = tap / 3, dx = tap - dy * 3;
        short8 a[4];
#pragma unroll
        for (int m = 0; m < 4; ++m) {
            int row = wq * 4 + m + dy, col = px + dx;
            a[m] = *(const short8*)(lds + (row * 18 + col) * 72 + half * 32 + kg * 8);
        }
#pragma unroll
        for (int nf = 0; nf < 8; ++nf) {
            short8 b0 = *(const short8*)(w0 + ((size_t)(ks * 8 + nf) * 64 + lane) * 8);
            short8 b1;
            if (NB == 2) b1 = *(const short8*)(w1 + ((size_t)(ks * 8 + nf) * 64 + lane) * 8);
#pragma unroll
            for (int m = 0; m < 4; ++m) {
                acc[m][nf] = __builtin_amdgcn_mfma_f32_16x16x32_bf16(a[m], b0, acc[m][nf], 0, 0, 0);
                if (NB == 2)
                    acc[m][nf] = __builtin_amdgcn_mfma_f32_16x16x32_bf16(a[m], b1, acc[m][nf], 0, 0, 0);
            }
        }
    }
}

// One timestep, both directions. grid (8,8,8): x-tiles, y-tiles, z = dir*4+b.
__global__ __launch_bounds__(256, 2)
void convlstm_mfma(const float* __restrict__ x, const unsigned short* __restrict__ wpk,
                   const float* __restrict__ biasf, const float* __restrict__ biasb,
                   float* __restrict__ cst, float* out, int t) {
    const int zb = blockIdx.z;
    const int dir = zb >> 2;
    const int b = zb & 3;
    const int x0 = blockIdx.x * 16, y0 = blockIdx.y * 16;
    const int ts = dir ? (S_ - 1 - t) : t;

    const float* xt = x + (size_t)(ts * B_ + b) * 32 * HW_;
    const float* bias = dir ? biasb : biasf;
    float* c = cst + (size_t)(dir * B_ + b) * 32 * HW_;
    float* outp = out + ((size_t)(t * B_ + b) * 64 + dir * 32) * HW_;
    const float* hprev = (t == 0) ? nullptr
                       : out + ((size_t)((t - 1) * B_ + b) * 64 + dir * 32) * HW_;
    const unsigned short* w_hi = wpk + (size_t)(dir * 2 + 0) * 73728;
    const unsigned short* w_lo = wpk + (size_t)(dir * 2 + 1) * 73728;

    __shared__ alignas(16) unsigned short atile[18 * 18 * 72];  // 46,656 B

    const int tid = threadIdx.x;
    const int lane = tid & 63, wq = tid >> 6;

    f32x4 acc[4][8];
#pragma unroll
    for (int m = 0; m < 4; ++m)
#pragma unroll
        for (int nf = 0; nf < 8; ++nf) acc[m][nf] = (f32x4)(0.f);

    // Phase 1: a_hi * (w_hi + w_lo)
    stage_tile(atile, xt, hprev, x0, y0, tid, 0);
    __syncthreads();
    compute_pass<2>(acc, atile, w_hi, w_lo, lane, wq);
    __syncthreads();
    // Phase 2: a_lo * w_hi
    stage_tile(atile, xt, hprev, x0, y0, tid, 1);
    __syncthreads();
    compute_pass<1>(acc, atile, w_hi, w_hi, lane, wq);

    // Epilogue: fully lane-local. D row=(lane>>4)*4+reg -> px, col=lane&15 -> co within nf.
    const int q0 = lane & 15, px0 = (lane >> 4) * 4;
    float bI[2], bF[2], bO[2], bG[2];
#pragma unroll
    for (int qs = 0; qs < 2; ++qs) {
        bI[qs] = bias[qs * 16 + q0];
        bF[qs] = bias[32 + qs * 16 + q0];
        bO[qs] = bias[64 + qs * 16 + q0];
        bG[qs] = bias[96 + qs * 16 + q0];
    }
#pragma unroll
    for (int m = 0; m < 4; ++m) {
        int gy = y0 + wq * 4 + m;
#pragma unroll
        for (int qs = 0; qs < 2; ++qs) {
            int q = qs * 16 + q0;
            f32x4 zi = acc[m][qs], zf = acc[m][2 + qs], zo = acc[m][4 + qs], zg = acc[m][6 + qs];
            size_t off = (size_t)q * HW_ + (size_t)gy * W_ + x0 + px0;
            f32x4 cold = (f32x4)(0.f);
            if (t) cold = *(const f32x4*)(c + off);
            f32x4 cn, hn;
#pragma unroll
            for (int r = 0; r < 4; ++r) {
                float I = sigf(zi[r] + bI[qs]);
                float F = sigf(zf[r] + bF[qs]);
                float O = sigf(zo[r] + bO[qs]);
                float G = tanhf_(zg[r] + bG[qs]);
                float cnr = F * cold[r] + I * G;
                cn[r] = cnr;
                hn[r] = O * tanhf_(cnr);
            }
            *(f32x4*)(c + off) = cn;
            *(f32x4*)(outp + off) = hn;
        }
    }
}

extern "C" void kernel_launch(void* const* d_in, const int* in_sizes, int n_in,
                              void* d_out, int out_size, void* d_ws, size_t ws_size,
                              hipStream_t stream) {
    const float* x  = (const float*)d_in[0];
    const float* Wf = (const float*)d_in[1];
    const float* bf = (const float*)d_in[2];
    const float* Wb = (const float*)d_in[3];
    const float* bb = (const float*)d_in[4];
    float* out = (float*)d_out;
    char* ws = (char*)d_ws;

    unsigned short* wpk = (unsigned short*)ws;      // 589,824 B (4 x 147,456)
    float* cst = (float*)(ws + 589824);             // 16,777,216 B

    prep_pack<<<dim3(72), dim3(256), 0, stream>>>(Wf, Wb, wpk);

    for (int t = 0; t < S_; ++t) {
        convlstm_mfma<<<dim3(8, 8, 8), dim3(256), 0, stream>>>(
            x, wpk, bf, bb, cst, out, t);
    }
}

// Round 4
// 1010.670 us; speedup vs baseline: 16.2829x; 2.3355x over previous
//
#include <hip/hip_runtime.h>

// BiCLSTM: S=16,B=4,Cin=32,Co=32,H=W=128. fp32 in/out.
// MFMA implicit-GEMM, K split by source half (x | h), hi+lo bf16 resident in LDS.
#define S_ 16
#define B_ 4
#define H_ 128
#define W_ 128
#define HW_ (H_ * W_)

typedef __attribute__((ext_vector_type(8))) short short8;
typedef __attribute__((ext_vector_type(4))) float f32x4;

__device__ __forceinline__ float bf2f(unsigned short u) {
    union { unsigned int i; float f; } v; v.i = ((unsigned int)u) << 16; return v.f;
}
__device__ __forceinline__ unsigned short f2bf(float f) {
    union { float f; unsigned int i; } v; v.f = f;
    unsigned int r = v.i + 0x7FFFu + ((v.i >> 16) & 1u);
    return (unsigned short)(r >> 16);
}
__device__ __forceinline__ float sigf(float x) { return 1.f / (1.f + __expf(-x)); }
__device__ __forceinline__ float tanhf_(float x) { return 2.f / (1.f + __expf(-2.f * x)) - 1.f; }

// Pack weights into MFMA B-fragment order, split hi/lo bf16.
// wpk: 4 streams [dir][s] each [ks=18][nf=8][lane=64][e=8] bf16.
// ks = tap*2 + half; ci = half*32 + (lane>>4)*8 + e; co = nf*16 + (lane&15).
__global__ void prep_pack(const float* __restrict__ Wf, const float* __restrict__ Wb,
                          unsigned short* __restrict__ wpk) {
    int id = blockIdx.x * 256 + threadIdx.x;  // 2*18*8*64 = 18432
    if (id >= 18432) return;
    int l = id & 63;
    int nf = (id >> 6) & 7;
    int ks = (id >> 9) % 18;
    int d = id / 9216;
    const float* Wsrc = d ? Wb : Wf;
    int tap = ks >> 1, half = ks & 1;
    int dy = tap / 3, dx = tap - dy * 3;
    int co = nf * 16 + (l & 15);
    size_t fo = ((size_t)(ks * 8 + nf) * 64 + l) * 8;
    unsigned short* dst_hi = wpk + (size_t)(d * 2 + 0) * 73728 + fo;
    unsigned short* dst_lo = wpk + (size_t)(d * 2 + 1) * 73728 + fo;
#pragma unroll
    for (int e = 0; e < 8; ++e) {
        int ci = half * 32 + (l >> 4) * 8 + e;
        float v = Wsrc[((co * 64 + ci) * 3 + dy) * 3 + dx];
        unsigned short h = f2bf(v);
        dst_hi[e] = h;
        dst_lo[e] = f2bf(v - bf2f(h));
    }
}

#define CI_PAD 40  // shorts per position: 32 ci + 8 pad (80B = 5 x 16B units -> uniform superbanks)
#define NPOS 324   // 18x18

__device__ __forceinline__ void stage_pos(unsigned short* __restrict__ Lhi,
                                          unsigned short* __restrict__ Llo,
                                          const float* __restrict__ src,  // 32-ch base (never null when called)
                                          int p, int x0, int y0) {
    int r = p / 18;
    int cc = p - r * 18;
    int gy = y0 + r - 1, gx = x0 + cc - 1;
    bool inb = ((unsigned)gy < 128u) && ((unsigned)gx < 128u);
    const float* g = src + (size_t)gy * W_ + gx;
    unsigned short* dhi = Lhi + p * CI_PAD;
    unsigned short* dlo = Llo + p * CI_PAD;
#pragma unroll
    for (int cb = 0; cb < 4; ++cb) {
        short8 vhi, vlo;
#pragma unroll
        for (int e = 0; e < 8; ++e) {
            float v = inb ? g[(cb * 8 + e) * HW_] : 0.f;
            unsigned short h = f2bf(v);
            vhi[e] = (short)h;
            vlo[e] = (short)f2bf(v - bf2f(h));
        }
        *(short8*)(dhi + cb * 8) = vhi;
        *(short8*)(dlo + cb * 8) = vlo;
    }
}

__device__ __forceinline__ void compute_half(f32x4 (&acc)[4][8],
                                             const unsigned short* __restrict__ Lhi,
                                             const unsigned short* __restrict__ Llo,
                                             const unsigned short* __restrict__ w_hi,
                                             const unsigned short* __restrict__ w_lo,
                                             int half, int lane, int wq) {
    const int px = lane & 15, kg = lane >> 4;
#pragma unroll 1
    for (int tap = 0; tap < 9; ++tap) {
        int dy = tap / 3, dx = tap - dy * 3;
        short8 ahi[4], alo[4];
#pragma unroll
        for (int m = 0; m < 4; ++m) {
            int pos = (wq * 4 + m + dy) * 18 + (px + dx);
            ahi[m] = *(const short8*)(Lhi + pos * CI_PAD + kg * 8);
            alo[m] = *(const short8*)(Llo + pos * CI_PAD + kg * 8);
        }
        int ks = tap * 2 + half;
        const unsigned short* bh = w_hi + (size_t)ks * 8 * 512;
        const unsigned short* bl = w_lo + (size_t)ks * 8 * 512;
#pragma unroll
        for (int nf = 0; nf < 8; ++nf) {
            short8 b0 = *(const short8*)(bh + ((size_t)nf * 64 + lane) * 8);
            short8 b1 = *(const short8*)(bl + ((size_t)nf * 64 + lane) * 8);
#pragma unroll
            for (int m = 0; m < 4; ++m) {
                acc[m][nf] = __builtin_amdgcn_mfma_f32_16x16x32_bf16(ahi[m], b0, acc[m][nf], 0, 0, 0);
                acc[m][nf] = __builtin_amdgcn_mfma_f32_16x16x32_bf16(ahi[m], b1, acc[m][nf], 0, 0, 0);
                acc[m][nf] = __builtin_amdgcn_mfma_f32_16x16x32_bf16(alo[m], b0, acc[m][nf], 0, 0, 0);
            }
        }
    }
}

// One timestep, both directions. grid (8,8,8): x-tiles, y-tiles, z = dir*4+b.
// h state lives in `out` (h(t-1) = out[t-1] slice, race-free across launches).
__global__ __launch_bounds__(256, 2)
void convlstm_mfma(const float* __restrict__ x, const unsigned short* __restrict__ wpk,
                   const float* __restrict__ biasf, const float* __restrict__ biasb,
                   float* __restrict__ cst, float* out, int t) {
    const int zb = blockIdx.z;
    const int dir = zb >> 2;
    const int b = zb & 3;
    const int x0 = blockIdx.x * 16, y0 = blockIdx.y * 16;
    const int ts = dir ? (S_ - 1 - t) : t;

    const float* xt = x + (size_t)(ts * B_ + b) * 32 * HW_;
    const float* bias = dir ? biasb : biasf;
    float* c = cst + (size_t)(dir * B_ + b) * 32 * HW_;
    float* outp = out + ((size_t)(t * B_ + b) * 64 + dir * 32) * HW_;
    const float* hprev = (t == 0) ? nullptr
                       : out + ((size_t)((t - 1) * B_ + b) * 64 + dir * 32) * HW_;
    const unsigned short* w_hi = wpk + (size_t)(dir * 2 + 0) * 73728;
    const unsigned short* w_lo = wpk + (size_t)(dir * 2 + 1) * 73728;

    __shared__ alignas(16) unsigned short lbuf[2 * NPOS * CI_PAD];  // 51,840 B
    unsigned short* Lhi = lbuf;
    unsigned short* Llo = lbuf + NPOS * CI_PAD;

    const int tid = threadIdx.x;
    const int lane = tid & 63, wq = tid >> 6;

    f32x4 acc[4][8];
#pragma unroll
    for (int m = 0; m < 4; ++m)
#pragma unroll
        for (int nf = 0; nf < 8; ++nf) acc[m][nf] = (f32x4)(0.f);

    // half 0: x channels
    stage_pos(Lhi, Llo, xt, tid, x0, y0);
    if (tid < NPOS - 256) stage_pos(Lhi, Llo, xt, tid + 256, x0, y0);
    __syncthreads();
    compute_half(acc, Lhi, Llo, w_hi, w_lo, 0, lane, wq);

    // half 1: h(t-1) channels (skip at t=0: h(-1)=0 contributes nothing)
    if (t > 0) {
        __syncthreads();
        stage_pos(Lhi, Llo, hprev, tid, x0, y0);
        if (tid < NPOS - 256) stage_pos(Lhi, Llo, hprev, tid + 256, x0, y0);
        __syncthreads();
        compute_half(acc, Lhi, Llo, w_hi, w_lo, 1, lane, wq);
    }

    // Epilogue: lane-local. D row=(lane>>4)*4+reg -> pixel, col=lane&15 -> co within nf.
    const int q0 = lane & 15, px0 = (lane >> 4) * 4;
    float bI[2], bF[2], bO[2], bG[2];
#pragma unroll
    for (int qs = 0; qs < 2; ++qs) {
        bI[qs] = bias[qs * 16 + q0];
        bF[qs] = bias[32 + qs * 16 + q0];
        bO[qs] = bias[64 + qs * 16 + q0];
        bG[qs] = bias[96 + qs * 16 + q0];
    }
#pragma unroll
    for (int m = 0; m < 4; ++m) {
        int gy = y0 + wq * 4 + m;
#pragma unroll
        for (int qs = 0; qs < 2; ++qs) {
            int q = qs * 16 + q0;
            f32x4 zi = acc[m][qs], zf = acc[m][2 + qs], zo = acc[m][4 + qs], zg = acc[m][6 + qs];
            size_t off = (size_t)q * HW_ + (size_t)gy * W_ + x0 + px0;
            f32x4 cold = (f32x4)(0.f);
            if (t) cold = *(const f32x4*)(c + off);
            f32x4 cn, hn;
#pragma unroll
            for (int r = 0; r < 4; ++r) {
                float I = sigf(zi[r] + bI[qs]);
                float F = sigf(zf[r] + bF[qs]);
                float O = sigf(zo[r] + bO[qs]);
                float G = tanhf_(zg[r] + bG[qs]);
                float cnr = F * cold[r] + I * G;
                cn[r] = cnr;
                hn[r] = O * tanhf_(cnr);
            }
            *(f32x4*)(c + off) = cn;
            *(f32x4*)(outp + off) = hn;
        }
    }
}

extern "C" void kernel_launch(void* const* d_in, const int* in_sizes, int n_in,
                              void* d_out, int out_size, void* d_ws, size_t ws_size,
                              hipStream_t stream) {
    const float* x  = (const float*)d_in[0];
    const float* Wf = (const float*)d_in[1];
    const float* bf = (const float*)d_in[2];
    const float* Wb = (const float*)d_in[3];
    const float* bb = (const float*)d_in[4];
    float* out = (float*)d_out;
    char* ws = (char*)d_ws;

    unsigned short* wpk = (unsigned short*)ws;      // 589,824 B (4 x 147,456)
    float* cst = (float*)(ws + 589824);             // 16,777,216 B

    prep_pack<<<dim3(72), dim3(256), 0, stream>>>(Wf, Wb, wpk);

    for (int t = 0; t < S_; ++t) {
        convlstm_mfma<<<dim3(8, 8, 8), dim3(256), 0, stream>>>(
            x, wpk, bf, bb, cst, out, t);
    }
}